// Round 4
// baseline (385.323 us; speedup 1.0000x reference)
//
#include <hip/hip_runtime.h>
#include <cstddef>

// Problem constants
constexpr int Bn  = 512;
constexpr int Dd  = 960;
constexpr int RL  = 16;
constexpr int RD  = 32;
constexpr int LPp = 16;
constexpr int LHh = 384;
constexpr int DP  = 358;
constexpr int DH  = 154;
constexpr int SEG = 192;   // H l-segment length (2 segments)

typedef float f32x4 __attribute__((ext_vector_type(4)));

// =====================================================================
// K1 vstream: V_part[b][p][d] = sum_{l in seg, l<len} A[l][p] * X[b][l][d]
// No LDS; accumulators in 64 VGPRs; 4-5 blocks/CU for latency hiding.
// grid: [0,1024) H (b=id>>1, seg=id&1); [1024,1536) P (seg 0, 16 rows).
// X streamed once, nontemporal (keeps params resident in L2).
// =====================================================================
__global__ __launch_bounds__(256, 4)
void vstream_kernel(const float* __restrict__ XH, const int* __restrict__ mH,
                    const float* __restrict__ AH, float* __restrict__ VH0,
                    float* __restrict__ VH1,
                    const float* __restrict__ XP, const int* __restrict__ mP,
                    const float* __restrict__ AP, float* __restrict__ VP)
{
    int id = blockIdx.x;
    const float* X; const int* mask; const float* A; float* V;
    int L, seg, seglen, b;
    if (id < 2 * Bn) {
        b = id >> 1; seg = id & 1;
        X = XH; mask = mH; A = AH; V = seg ? VH1 : VH0;
        L = LHh; seglen = SEG;
    } else {
        b = id - 2 * Bn; seg = 0;
        X = XP; mask = mP; A = AP; V = VP;
        L = LPp; seglen = LPp;
    }
    const int t = threadIdx.x;

    // len = popcount of contiguous-prefix mask row
    __shared__ int s_len;
    if (t == 0) s_len = 0;
    __syncthreads();
    int loc = 0;
    for (int i = t; i < L; i += 256) loc += mask[(size_t)b * L + i];
    if (loc) atomicAdd(&s_len, loc);
    __syncthreads();
    const int len = s_len;

    if (t >= 240) return;              // 240 threads x 4 d-cols = 960

    const int l0 = seg * seglen;
    const int l1 = min(len, l0 + seglen);

    float v[RL][4];
    #pragma unroll
    for (int p = 0; p < RL; ++p)
        #pragma unroll
        for (int q = 0; q < 4; ++q) v[p][q] = 0.f;

    const float* xrow = X + ((size_t)b * L + l0) * Dd + 4 * t;
    #pragma unroll 2
    for (int l = l0; l < l1; ++l) {
        f32x4 xv = __builtin_nontemporal_load((const f32x4*)xrow);
        xrow += Dd;
        float a[RL];
        *(f32x4*)&a[0]  = *(const f32x4*)(A + (size_t)l * RL + 0);
        *(f32x4*)&a[4]  = *(const f32x4*)(A + (size_t)l * RL + 4);
        *(f32x4*)&a[8]  = *(const f32x4*)(A + (size_t)l * RL + 8);
        *(f32x4*)&a[12] = *(const f32x4*)(A + (size_t)l * RL + 12);
        #pragma unroll
        for (int p = 0; p < RL; ++p) {
            v[p][0] = fmaf(a[p], xv[0], v[p][0]);
            v[p][1] = fmaf(a[p], xv[1], v[p][1]);
            v[p][2] = fmaf(a[p], xv[2], v[p][2]);
            v[p][3] = fmaf(a[p], xv[3], v[p][3]);
        }
    }
    // store partial V (zeros if segment empty -> K2 just sums)
    #pragma unroll
    for (int p = 0; p < RL; ++p)
        *(f32x4*)(V + ((size_t)b * RL + p) * Dd + 4 * t) = *(f32x4*)&v[p][0];
}

// =====================================================================
// K2 uz: per batch b:
//   U[p][r] = sum_d (V0[p][d] (+ V1[p][d])) * Bc[d][r]   -> Ush (LDS 2KB)
//   z[b][j] = sum_i Ush[i] * Hc[i][j]
// grid: [0,512) P, [512,1024) H. Only 2KB LDS -> high occupancy.
// V reads are lane-uniform within 32-lane groups (L1 broadcast);
// Bc reads are one 128B line per (d, wave).
// =====================================================================
__global__ __launch_bounds__(256)
void uz_kernel(const float* __restrict__ VP, const float* __restrict__ BcP,
               const float* __restrict__ HcP, float* __restrict__ zP,
               const float* __restrict__ VH0, const float* __restrict__ VH1,
               const float* __restrict__ BcH, const float* __restrict__ HcH,
               float* __restrict__ zH)
{
    const int bid = blockIdx.x;
    const bool isP = bid < Bn;
    const int b = isP ? bid : bid - Bn;
    const int t = threadIdx.x;
    const int p = t >> 5, r = t & 31;

    const float* V0 = (isP ? VP : VH0) + (size_t)b * RL * Dd;
    const float* V1 = VH1 + (size_t)b * RL * Dd;   // H only
    const float* Bc = isP ? BcP : BcH;
    const float* Hc = isP ? HcP : HcH;
    float*       z  = isP ? zP  : zH;
    const int dmod  = isP ? DP  : DH;

    __shared__ float Ush[RL * RD];

    float u0 = 0.f, u1 = 0.f;
    if (isP) {
        #pragma unroll 2
        for (int d = 0; d < Dd; d += 4) {
            f32x4 a0 = *(const f32x4*)(V0 + (size_t)p * Dd + d);
            f32x4 a1 = *(const f32x4*)(V0 + (size_t)(p + 8) * Dd + d);
            #pragma unroll
            for (int q = 0; q < 4; ++q) {
                float bc = Bc[(size_t)(d + q) * RD + r];
                u0 = fmaf(a0[q], bc, u0);
                u1 = fmaf(a1[q], bc, u1);
            }
        }
    } else {
        #pragma unroll 2
        for (int d = 0; d < Dd; d += 4) {
            f32x4 a0 = *(const f32x4*)(V0 + (size_t)p * Dd + d);
            f32x4 b0 = *(const f32x4*)(V1 + (size_t)p * Dd + d);
            f32x4 a1 = *(const f32x4*)(V0 + (size_t)(p + 8) * Dd + d);
            f32x4 b1 = *(const f32x4*)(V1 + (size_t)(p + 8) * Dd + d);
            a0 += b0; a1 += b1;
            #pragma unroll
            for (int q = 0; q < 4; ++q) {
                float bc = Bc[(size_t)(d + q) * RD + r];
                u0 = fmaf(a0[q], bc, u0);
                u1 = fmaf(a1[q], bc, u1);
            }
        }
    }
    Ush[p * RD + r]       = u0;
    Ush[(p + 8) * RD + r] = u1;
    __syncthreads();

    for (int j = t; j < dmod; j += 256) {
        float acc = 0.f;
        #pragma unroll 8
        for (int i = 0; i < RL * RD; ++i)
            acc = fmaf(Ush[i], Hc[(size_t)i * dmod + j], acc);
        z[(size_t)b * dmod + j] = acc;
    }
}

// =====================================================================
// K3/K4 mlp2: C = A(512,K) @ W(K,N) + bias, P and H fused in one grid.
//   MODE 0: h = relu(C * g/sqrt(1+eps) + beta) -> out (512,N) pitch N
//   MODE 1: C -> d_out[m*(DP+DH) + ooff + c]   (concat store)
// =====================================================================
template <int MODE>
__global__ __launch_bounds__(256)
void mlp2_kernel(const float* __restrict__ AaP, const float* __restrict__ WP,
                 const float* __restrict__ biasP, const float* __restrict__ gPv,
                 const float* __restrict__ betaPv, float* __restrict__ outP,
                 const float* __restrict__ AaH, const float* __restrict__ WH,
                 const float* __restrict__ biasH, const float* __restrict__ gHv,
                 const float* __restrict__ betaHv, float* __restrict__ outH,
                 int nbP)
{
    const float *Aa, *W, *bias, *g, *beta; float* out;
    int K, N, n0, ooff;
    if ((int)blockIdx.y < nbP) {
        Aa = AaP; W = WP; bias = biasP; g = gPv; beta = betaPv; out = outP;
        K = DP; N = DP; n0 = blockIdx.y * 64; ooff = 0;
    } else {
        Aa = AaH; W = WH; bias = biasH; g = gHv; beta = betaHv; out = outH;
        K = DH; N = DH; n0 = (blockIdx.y - nbP) * 64; ooff = DP;
    }
    const int ostride = (MODE == 0) ? N : (DP + DH);
    if (MODE == 0) ooff = 0;

    constexpr int TM = 64, TN = 64, KC = 32;
    __shared__ float AsT[KC][TM + 4];
    __shared__ float Ws[KC][TN];
    const int t  = threadIdx.x;
    const int m0 = blockIdx.x * TM;
    const int r0 = (t >> 4) << 2;
    const int c0 = (t & 15) << 2;
    float acc[4][4] = {};

    for (int k0 = 0; k0 < K; k0 += KC) {
        for (int i = t; i < TM * KC; i += 256) {
            int row = i >> 5, kk = i & 31;
            int kg = k0 + kk;
            AsT[kk][row] = (kg < K) ? Aa[(size_t)(m0 + row) * K + kg] : 0.f;
        }
        for (int i = t; i < KC * TN; i += 256) {
            int kk = i >> 6, c = i & 63;
            int kg = k0 + kk, cg = n0 + c;
            Ws[kk][c] = (kg < K && cg < N) ? W[(size_t)kg * N + cg] : 0.f;
        }
        __syncthreads();
        #pragma unroll
        for (int kk = 0; kk < KC; ++kk) {
            float4 av = *(const float4*)&AsT[kk][r0];
            float4 wv = *(const float4*)&Ws[kk][c0];
            const float a[4] = {av.x, av.y, av.z, av.w};
            const float w[4] = {wv.x, wv.y, wv.z, wv.w};
            #pragma unroll
            for (int i = 0; i < 4; ++i)
                #pragma unroll
                for (int j = 0; j < 4; ++j)
                    acc[i][j] = fmaf(a[i], w[j], acc[i][j]);
        }
        __syncthreads();
    }

    const float bscale = rsqrtf(1.f + 1e-5f);
    #pragma unroll
    for (int j = 0; j < 4; ++j) {
        int c = n0 + c0 + j;
        if (c < N) {
            float bb = bias[c];
            float gg = 0.f, be = 0.f;
            if constexpr (MODE == 0) { gg = g[c] * bscale; be = beta[c]; }
            #pragma unroll
            for (int i = 0; i < 4; ++i) {
                int m = m0 + r0 + i;
                float v = acc[i][j] + bb;
                if constexpr (MODE == 0) {
                    v = fmaf(v, gg, be);
                    v = fmaxf(v, 0.f);
                    out[(size_t)m * N + c] = v;
                } else {
                    out[(size_t)m * ostride + ooff + c] = v;
                }
            }
        }
    }
}

// =====================================================================
extern "C" void kernel_launch(void* const* d_in, const int* in_sizes, int n_in,
                              void* d_out, int out_size, void* d_ws, size_t ws_size,
                              hipStream_t stream)
{
    const float* emb_P  = (const float*)d_in[0];
    const float* emb_H  = (const float*)d_in[1];
    const int*   mask_P = (const int*)  d_in[2];
    const int*   mask_H = (const int*)  d_in[3];
    const float* B_cP   = (const float*)d_in[4];
    const float* A_cP   = (const float*)d_in[5];
    const float* H_cP   = (const float*)d_in[6];
    const float* W1P    = (const float*)d_in[7];
    const float* b1P    = (const float*)d_in[8];
    const float* gP     = (const float*)d_in[9];
    const float* betaP  = (const float*)d_in[10];
    const float* W2P    = (const float*)d_in[11];
    const float* b2P    = (const float*)d_in[12];
    const float* B_cH   = (const float*)d_in[13];
    const float* A_cH   = (const float*)d_in[14];
    const float* H_cH   = (const float*)d_in[15];
    const float* W1H    = (const float*)d_in[16];
    const float* b1H    = (const float*)d_in[17];
    const float* gH     = (const float*)d_in[18];
    const float* betaH  = (const float*)d_in[19];
    const float* W2H    = (const float*)d_in[20];
    const float* b2H    = (const float*)d_in[21];
    float* outp = (float*)d_out;

    // workspace layout (floats)
    float* ws   = (float*)d_ws;
    const size_t VSZ = (size_t)Bn * RL * Dd;      // 7,864,320
    float* V_H0 = ws;
    float* V_H1 = V_H0 + VSZ;
    float* V_P  = V_H1 + VSZ;
    float* z_P  = V_P  + VSZ;                      // 512*358
    float* z_H  = z_P  + (size_t)Bn * DP;          // 512*154
    float* h_P  = z_H  + (size_t)Bn * DH;
    float* h_H  = h_P  + (size_t)Bn * DP;

    dim3 blk(256);

    // K1: V partials (H: 2 segments, P: 1)
    vstream_kernel<<<dim3(3 * Bn), blk, 0, stream>>>(
        emb_H, mask_H, A_cH, V_H0, V_H1,
        emb_P, mask_P, A_cP, V_P);

    // K2: U = (sum V_parts) Bc ; z = vec(U) Hc
    uz_kernel<<<dim3(2 * Bn), blk, 0, stream>>>(
        V_P, B_cP, H_cP, z_P,
        V_H0, V_H1, B_cH, H_cH, z_H);

    // K3: layer 1 (BN-scale + ReLU): P tiles y=0..5, H tiles y=6..8
    mlp2_kernel<0><<<dim3(8, 9), blk, 0, stream>>>(
        z_P, W1P, b1P, gP, betaP, h_P,
        z_H, W1H, b1H, gH, betaH, h_H, 6);

    // K4: layer 2 + concat store into d_out
    mlp2_kernel<1><<<dim3(8, 9), blk, 0, stream>>>(
        h_P, W2P, b2P, nullptr, nullptr, outp,
        h_H, W2H, b2H, nullptr, nullptr, outp, 6);
}